// Round 1
// baseline (149.988 us; speedup 1.0000x reference)
//
#include <hip/hip_runtime.h>

#define W 512
#define PLANE (W * W)            // 262144
#define NBATCH 32                // 4*8
#define NPTS (NBATCH * PLANE)    // 8388608 spatial points per channel
#define NBLK 2048                // 32 batches * 64 strips of 8 rows

static constexpr float DT_INV = 100.0f;   // 1/DT
static constexpr float NU_C   = 0.001f;
// DX = 1.0 -> grad scale 0.5, laplacian scale 1.0

// v6: LDS-free, barrier-free stencil.
// Each block: one batch, 8-row strip. Thread t: half-wave row rr = t>>5,
// 32 lanes * float4 quads at stride 128 cover the full 512-col row, so
// x-neighbors (including the periodic wrap) are resolved entirely with
// width-32 shuffles. y-halo rows load straight from global (L2/L3 absorbs
// the 3x u_pred re-read; HBM compulsory traffic unchanged). No mid-kernel
// __syncthreads -> no vmcnt(0) drain stall; occupancy no longer LDS-capped.
__global__ __launch_bounds__(256) void ns_loss_v6(
    const float* __restrict__ u_pred,
    const float* __restrict__ u_prev,
    float* __restrict__ partial)
{
    __shared__ float red[16];               // end-reduction only (64 B)

    const int t   = threadIdx.x;
    const int l32 = t & 31;
    const int rr  = t >> 5;                 // row within strip, 0..7
    const int cx  = l32 << 2;               // base column of quad 0

    // bijective XCD swizzle (2048 % 8 == 0): all 64 strips of a batch
    // land on one XCD -> y-halo re-reads hit that XCD's L2.
    const int bid = blockIdx.x;
    const int lid = ((bid & 7) << 8) | (bid >> 3);

    const int b  = lid >> 6;                // 0..31
    const int y0 = (lid & 63) << 3;         // strip base row
    const int yc = y0 + rr;
    const int ym = (yc - 1) & 511;
    const int yp = (yc + 1) & 511;

    const float* u0 = u_pred + (size_t)b * (2 * PLANE);
    const float* v0 = u0 + PLANE;
    const float* q0 = u_prev + (size_t)b * (2 * PLANE);
    const float* q1 = q0 + PLANE;

    const float* uC = u0 + yc * W + cx;
    const float* uM = u0 + ym * W + cx;
    const float* uP = u0 + yp * W + cx;
    const float* vC = v0 + yc * W + cx;
    const float* vM = v0 + ym * W + cx;
    const float* vP = v0 + yp * W + cx;
    const float* pU = q0 + yc * W + cx;
    const float* pV = q1 + yc * W + cx;

    // ---- center rows: 8 quads, then resolve x-neighbor edges in-wave ----
    float4 uc[4], vc[4];
#pragma unroll
    for (int g = 0; g < 4; ++g) {
        uc[g] = *(const float4*)(uC + (g << 7));
        vc[g] = *(const float4*)(vC + (g << 7));
    }

    float uLs[4], uRs[4], vLs[4], vRs[4];
#pragma unroll
    for (int g = 0; g < 4; ++g) {
        uLs[g] = __shfl(uc[g].w, (l32 - 1) & 31, 32);
        uRs[g] = __shfl(uc[g].x, (l32 + 1) & 31, 32);
        vLs[g] = __shfl(vc[g].w, (l32 - 1) & 31, 32);
        vRs[g] = __shfl(vc[g].x, (l32 + 1) & 31, 32);
    }

    float s_pde = 0.0f, s_div = 0.0f;
#pragma unroll
    for (int g = 0; g < 4; ++g) {
        const float4 um = *(const float4*)(uM + (g << 7));
        const float4 up = *(const float4*)(uP + (g << 7));
        const float4 vm = *(const float4*)(vM + (g << 7));
        const float4 vp = *(const float4*)(vP + (g << 7));
        const float4 pu = *(const float4*)(pU + (g << 7));
        const float4 pv = *(const float4*)(pV + (g << 7));

        // periodic x-wrap: lane 0's left neighbor lives in quad g-1 (lane 31),
        // lane 31's right neighbor in quad g+1 (lane 0) — same thread-local
        // shuffle results, different quad index.
        const float uL = (l32 == 0)  ? uLs[(g + 3) & 3] : uLs[g];
        const float uR = (l32 == 31) ? uRs[(g + 1) & 3] : uRs[g];
        const float vL = (l32 == 0)  ? vLs[(g + 3) & 3] : vLs[g];
        const float vR = (l32 == 31) ? vRs[(g + 1) & 3] : vRs[g];

        const float ua[6]  = {uL, uc[g].x, uc[g].y, uc[g].z, uc[g].w, uR};
        const float va[6]  = {vL, vc[g].x, vc[g].y, vc[g].z, vc[g].w, vR};
        const float umA[4] = {um.x, um.y, um.z, um.w};
        const float upA[4] = {up.x, up.y, up.z, up.w};
        const float vmA[4] = {vm.x, vm.y, vm.z, vm.w};
        const float vpA[4] = {vp.x, vp.y, vp.z, vp.w};
        const float puA[4] = {pu.x, pu.y, pu.z, pu.w};
        const float pvA[4] = {pv.x, pv.y, pv.z, pv.w};

#pragma unroll
        for (int j = 0; j < 4; ++j) {
            const float u   = ua[j + 1];
            const float v   = va[j + 1];
            const float u_x = (ua[j + 2] - ua[j]) * 0.5f;
            const float v_x = (va[j + 2] - va[j]) * 0.5f;
            const float u_y = (upA[j] - umA[j]) * 0.5f;
            const float v_y = (vpA[j] - vmA[j]) * 0.5f;
            const float lap_u = upA[j] + umA[j] + ua[j + 2] + ua[j] - 4.0f * u;
            const float lap_v = vpA[j] + vmA[j] + va[j + 2] + va[j] - 4.0f * v;
            const float rx = (u - puA[j]) * DT_INV + u * u_x + v * u_y - NU_C * lap_u;
            const float ry = (v - pvA[j]) * DT_INV + u * v_x + v * v_y - NU_C * lap_v;
            const float dv = u_x + v_y;
            s_pde += rx * rx + ry * ry;
            s_div += dv * dv;
        }
    }

    // ---- reduction (identical tree to v5 -> bit-identical partials) ----
#pragma unroll
    for (int off = 32; off > 0; off >>= 1) {
        s_pde += __shfl_down(s_pde, off);
        s_div += __shfl_down(s_div, off);
    }

    const int lane = t & 63;
    const int wv   = t >> 6;
    if (lane == 0) { red[wv] = s_pde; red[8 + wv] = s_div; }
    __syncthreads();
    if (t == 0) {
        partial[lid]        = red[0] + red[1] + red[2] + red[3];
        partial[NBLK + lid] = red[8] + red[9] + red[10] + red[11];
    }
}

__global__ __launch_bounds__(256) void ns_reduce(
    const float* __restrict__ partial,
    float* __restrict__ out)
{
    double sp = 0.0, sd = 0.0;
    for (int i = threadIdx.x; i < NBLK; i += 256) {
        sp += (double)partial[i];
        sd += (double)partial[NBLK + i];
    }
#pragma unroll
    for (int off = 32; off > 0; off >>= 1) {
        sp += __shfl_down(sp, off);
        sd += __shfl_down(sd, off);
    }
    __shared__ double ssp[4], ssd[4];
    const int lane = threadIdx.x & 63;
    const int wv   = threadIdx.x >> 6;
    if (lane == 0) { ssp[wv] = sp; ssd[wv] = sd; }
    __syncthreads();
    if (threadIdx.x == 0) {
        const double tp = ssp[0] + ssp[1] + ssp[2] + ssp[3];
        const double td = ssd[0] + ssd[1] + ssd[2] + ssd[3];
        const double inv = 1.0 / (double)NPTS;
        const double pde = tp * inv;
        const double dvl = td * inv;
        out[0] = (float)(pde + 0.1 * dvl);
        out[1] = (float)pde;
        out[2] = (float)dvl;
    }
}

extern "C" void kernel_launch(void* const* d_in, const int* in_sizes, int n_in,
                              void* d_out, int out_size, void* d_ws, size_t ws_size,
                              hipStream_t stream) {
    const float* u_pred = (const float*)d_in[0];
    const float* u_prev = (const float*)d_in[1];
    float* out = (float*)d_out;
    float* partial = (float*)d_ws;   // 2*NBLK floats = 16 KB

    ns_loss_v6<<<NBLK, 256, 0, stream>>>(u_pred, u_prev, partial);
    ns_reduce<<<1, 256, 0, stream>>>(partial, out);
}

// Round 2
// 146.160 us; speedup vs baseline: 1.0262x; 1.0262x over previous
//
#include <hip/hip_runtime.h>

#define W 512
#define PLANE (W * W)            // 262144
#define NBATCH 32                // 4*8
#define NPTS (NBATCH * PLANE)    // 8388608 spatial points per channel
#define SEG 4                    // rows marched per wave
#define NBLK 1024                // 4096 waves = 32 batches * 128 segments

static constexpr float DT_INV = 100.0f;   // 1/DT
static constexpr float NU_C   = 0.001f;
// DX = 1.0 -> grad scale 0.5, laplacian scale 1.0

// v7: rolling-row register march, software-pipelined.
// One wave owns a full 512-col row (64 lanes x 2 float4 quads at cols
// 4l and 4l+256) and marches a 4-row segment, keeping rows y-1,y,y+1 of
// u and v in registers. Each step loads ONE new row per array and the
// loads for step k+1 are issued before step k's compute -> each vmcnt
// wait is covered by a full compute step + 4-way wave interleave.
// u_pred rows read 1.5x (6 rows per 4-row segment) vs 3x in v6;
// no LDS staging, no mid-kernel barrier. __launch_bounds__(256,4)
// pins VGPR<=128 so all 4096 waves (4/SIMD) are co-resident.
__global__ __launch_bounds__(256, 4) void ns_loss_v7(
    const float* __restrict__ u_pred,
    const float* __restrict__ u_prev,
    float* __restrict__ partial)
{
    __shared__ float red[16];               // end-reduction only

    const int t  = threadIdx.x;
    const int l  = t & 63;
    const int wv = t >> 6;

    // bijective XCD swizzle (1024 % 8 == 0): 128 consecutive lids per XCD
    // = 4 batches per XCD; segments sharing halo rows land on one L2.
    const int bid = blockIdx.x;
    const int lid = ((bid & 7) << 7) | (bid >> 3);

    const int gw = (lid << 2) | wv;         // global wave 0..4095
    const int b  = gw >> 7;                 // batch 0..31
    const int y0 = (gw & 127) << 2;         // segment base row

    const float* u0 = u_pred + (size_t)b * (2 * PLANE);
    const float* v0 = u0 + PLANE;
    const float* q0 = u_prev + (size_t)b * (2 * PLANE);
    const float* q1 = q0 + PLANE;

    const int c0 = l << 2;                  // quad g adds 256 cols

    auto LD = [&](const float* base, int row, int g) -> float4 {
        return *(const float4*)(base + row * W + c0 + (g << 8));
    };

    // ---- prologue: rows y0-1, y0, y0+1 of u,v + prev row y0 ----
    float4 um[2], uc[2], un[2], vm[2], vcr[2], vn[2], pu[2], pv[2];
    const int ymr = (y0 - 1) & 511;
#pragma unroll
    for (int g = 0; g < 2; ++g) {
        um[g]  = LD(u0, ymr, g);
        vm[g]  = LD(v0, ymr, g);
        uc[g]  = LD(u0, y0, g);
        vcr[g] = LD(v0, y0, g);
        un[g]  = LD(u0, y0 + 1, g);
        vn[g]  = LD(v0, y0 + 1, g);
        pu[g]  = LD(q0, y0, g);
        pv[g]  = LD(q1, y0, g);
    }

    float s_pde = 0.0f, s_div = 0.0f;

#pragma unroll
    for (int k = 0; k < SEG; ++k) {
        // ---- prefetch step k+1's new rows before computing step k ----
        float4 nu[2], nv[2], npu[2], npv[2];
        if (k < SEG - 1) {
            const int yn = (y0 + k + 2) & 511;   // wraps only at y0=508
            const int yq = y0 + k + 1;           // <= 511, no wrap
#pragma unroll
            for (int g = 0; g < 2; ++g) {
                nu[g]  = LD(u0, yn, g);
                nv[g]  = LD(v0, yn, g);
                npu[g] = LD(q0, yq, g);
                npv[g] = LD(q1, yq, g);
            }
        }

        // ---- x-neighbor edges via width-64 shuffles ----
        float uLs[2], uRs[2], vLs[2], vRs[2];
#pragma unroll
        for (int g = 0; g < 2; ++g) {
            uLs[g] = __shfl(uc[g].w,  (l + 63) & 63, 64);
            uRs[g] = __shfl(uc[g].x,  (l + 1)  & 63, 64);
            vLs[g] = __shfl(vcr[g].w, (l + 63) & 63, 64);
            vRs[g] = __shfl(vcr[g].x, (l + 1)  & 63, 64);
        }

#pragma unroll
        for (int g = 0; g < 2; ++g) {
            // periodic x-wrap: quad 0 lane 0's left neighbor is col 511
            // (lane 63 of quad 1); quad 1 lane 63's right is col 0
            // (lane 0 of quad 0) — cross-quad pick of the same shuffles.
            const float uL = (l == 0)  ? uLs[g ^ 1] : uLs[g];
            const float uR = (l == 63) ? uRs[g ^ 1] : uRs[g];
            const float vL = (l == 0)  ? vLs[g ^ 1] : vLs[g];
            const float vR = (l == 63) ? vRs[g ^ 1] : vRs[g];

            const float ua[6]  = {uL, uc[g].x, uc[g].y, uc[g].z, uc[g].w, uR};
            const float va[6]  = {vL, vcr[g].x, vcr[g].y, vcr[g].z, vcr[g].w, vR};
            const float umA[4] = {um[g].x, um[g].y, um[g].z, um[g].w};
            const float upA[4] = {un[g].x, un[g].y, un[g].z, un[g].w};
            const float vmA[4] = {vm[g].x, vm[g].y, vm[g].z, vm[g].w};
            const float vpA[4] = {vn[g].x, vn[g].y, vn[g].z, vn[g].w};
            const float puA[4] = {pu[g].x, pu[g].y, pu[g].z, pu[g].w};
            const float pvA[4] = {pv[g].x, pv[g].y, pv[g].z, pv[g].w};

#pragma unroll
            for (int j = 0; j < 4; ++j) {
                const float u   = ua[j + 1];
                const float v   = va[j + 1];
                const float u_x = (ua[j + 2] - ua[j]) * 0.5f;
                const float v_x = (va[j + 2] - va[j]) * 0.5f;
                const float u_y = (upA[j] - umA[j]) * 0.5f;
                const float v_y = (vpA[j] - vmA[j]) * 0.5f;
                const float lap_u = upA[j] + umA[j] + ua[j + 2] + ua[j] - 4.0f * u;
                const float lap_v = vpA[j] + vmA[j] + va[j + 2] + va[j] - 4.0f * v;
                const float rx = (u - puA[j]) * DT_INV + u * u_x + v * u_y - NU_C * lap_u;
                const float ry = (v - pvA[j]) * DT_INV + u * v_x + v * v_y - NU_C * lap_v;
                const float dv = u_x + v_y;
                s_pde += rx * rx + ry * ry;
                s_div += dv * dv;
            }
        }

        // ---- rotate rows (SSA renames under full unroll) ----
        if (k < SEG - 1) {
#pragma unroll
            for (int g = 0; g < 2; ++g) {
                um[g] = uc[g];  uc[g] = un[g];   un[g] = nu[g];
                vm[g] = vcr[g]; vcr[g] = vn[g];  vn[g] = nv[g];
                pu[g] = npu[g]; pv[g] = npv[g];
            }
        }
    }

    // ---- reduction ----
#pragma unroll
    for (int off = 32; off > 0; off >>= 1) {
        s_pde += __shfl_down(s_pde, off);
        s_div += __shfl_down(s_div, off);
    }

    if (l == 0) { red[wv] = s_pde; red[8 + wv] = s_div; }
    __syncthreads();
    if (t == 0) {
        partial[lid]        = red[0] + red[1] + red[2] + red[3];
        partial[NBLK + lid] = red[8] + red[9] + red[10] + red[11];
    }
}

__global__ __launch_bounds__(256) void ns_reduce(
    const float* __restrict__ partial,
    float* __restrict__ out)
{
    double sp = 0.0, sd = 0.0;
    for (int i = threadIdx.x; i < NBLK; i += 256) {
        sp += (double)partial[i];
        sd += (double)partial[NBLK + i];
    }
#pragma unroll
    for (int off = 32; off > 0; off >>= 1) {
        sp += __shfl_down(sp, off);
        sd += __shfl_down(sd, off);
    }
    __shared__ double ssp[4], ssd[4];
    const int lane = threadIdx.x & 63;
    const int wv   = threadIdx.x >> 6;
    if (lane == 0) { ssp[wv] = sp; ssd[wv] = sd; }
    __syncthreads();
    if (threadIdx.x == 0) {
        const double tp = ssp[0] + ssp[1] + ssp[2] + ssp[3];
        const double td = ssd[0] + ssd[1] + ssd[2] + ssd[3];
        const double inv = 1.0 / (double)NPTS;
        const double pde = tp * inv;
        const double dvl = td * inv;
        out[0] = (float)(pde + 0.1 * dvl);
        out[1] = (float)pde;
        out[2] = (float)dvl;
    }
}

extern "C" void kernel_launch(void* const* d_in, const int* in_sizes, int n_in,
                              void* d_out, int out_size, void* d_ws, size_t ws_size,
                              hipStream_t stream) {
    const float* u_pred = (const float*)d_in[0];
    const float* u_prev = (const float*)d_in[1];
    float* out = (float*)d_out;
    float* partial = (float*)d_ws;   // 2*NBLK floats = 8 KB

    ns_loss_v7<<<NBLK, 256, 0, stream>>>(u_pred, u_prev, partial);
    ns_reduce<<<1, 256, 0, stream>>>(partial, out);
}